// Round 2
// baseline (118.056 us; speedup 1.0000x reference)
//
#include <hip/hip_runtime.h>

// Problem: b=4, c=64, h=w=128, ks=3, N=9, offset ch=18, oc=64. Padded HP=130.
#define BATCH 4
#define CH    64
#define HH    128
#define WW    128
#define HW    (HH*WW)
#define HP    130
#define NOFF  18
#define OC    64

typedef _Float16 half8 __attribute__((ext_vector_type(8)));
typedef _Float16 half4 __attribute__((ext_vector_type(4)));
typedef float f32x4 __attribute__((ext_vector_type(4)));

// ws layout (bytes):
//   wf  @ 0      : 36864 f16 (main A-frags)    pf @ 73728: 18432 f16
//   x0t @ 110592 : 4*130*130*64 f16 (padded NHWC, zero ring)
//   x1t @ 8763392: same                        total 17416192 B
#define WF_OFF  0
#define PF_OFF  73728
#define X0T_OFF 110592
#define X1T_OFF 8763392

// ---------------------------------------------------------------------------
// Kernel A: blocks 0..2047 transpose half-rows NCHW f32 -> padded NHWC f16;
// 2048..2063 zero ring rows; 2064..2279 A-fragments (k-major t = k*64+c).
// ---------------------------------------------------------------------------
__global__ __launch_bounds__(256) void prep_all(
    const float* __restrict__ x0, const float* __restrict__ x1,
    const float* __restrict__ cw, const float* __restrict__ pw,
    _Float16* __restrict__ x0t, _Float16* __restrict__ x1t,
    _Float16* __restrict__ wf, _Float16* __restrict__ pf) {
  int blk = blockIdx.x, tid = threadIdx.x;
  if (blk < 2048) {
    __shared__ float tile[64 * 66];
    int jh = blk & 1, i = (blk >> 1) & 127, b = (blk >> 8) & 3, which = blk >> 10;
    const float* src = which ? x1 : x0;
    _Float16* dst = which ? x1t : x0t;
#pragma unroll
    for (int it = 0; it < 4; it++) {
      int idx = it * 256 + tid;            // 1024 float4 = 64c x 64j
      int c = idx >> 4, j4 = (idx & 15) << 2;
      float4 v = *(const float4*)(src + (size_t)(b * CH + c) * HW + i * WW + jh * 64 + j4);
      *(float4*)&tile[c * 66 + j4] = v;
    }
    __syncthreads();
    int jl = tid >> 2, cq = (tid & 3) << 4;
    _Float16* dp = dst + ((size_t)(b * HP + i + 1) * HP + (jh * 64 + jl + 1)) * CH + cq;
#pragma unroll
    for (int h = 0; h < 2; h++) {
      half8 v;
#pragma unroll
      for (int cc = 0; cc < 8; cc++) v[cc] = (_Float16)tile[(cq + h * 8 + cc) * 66 + jl];
      *(half8*)(dp + h * 8) = v;
    }
    if (tid < 8) {                          // ring column jo=0 (jh0) / jo=129 (jh1)
      int jo = jh ? (HP - 1) : 0;
      _Float16* zp = dst + ((size_t)(b * HP + i + 1) * HP + jo) * CH + tid * 8;
      int4 z = {0, 0, 0, 0};
      *(int4*)zp = z;
    }
  } else if (blk < 2064) {
    int z = blk - 2048;
    int which = z >> 3, b = (z >> 1) & 3, top = z & 1;
    _Float16* dst = (which ? x1t : x0t) + ((size_t)(b * HP + top * (HP - 1)) * HP) * CH;
    int4 zz = {0, 0, 0, 0};
    for (int e = tid; e < 1040; e += 256) *(int4*)((char*)dst + e * 16) = zz;
  } else {
    int gid = (blk - 2064) * 256 + tid;     // 216*256 = 36864 + 18432
    if (gid < 36864) {
      int j = gid & 7, lane = (gid >> 3) & 63, mt = (gid >> 9) & 3, s = gid >> 11;
      int oc = mt * 16 + (lane & 15);
      int t = s * 32 + (lane >> 4) * 8 + j;
      int k = t >> 6, c = t & 63;
      wf[gid] = (_Float16)cw[(oc * CH + c) * 9 + k];
    } else {
      int g = gid - 36864;
      int j = g & 7, lane = (g >> 3) & 63, mt = (g >> 9) & 1, s = g >> 10;
      int o = mt * 16 + (lane & 15);
      int t = s * 32 + (lane >> 4) * 8 + j;
      int k = t >> 6, c = t & 63;
      pf[g] = (o < NOFF) ? (_Float16)pw[(o * CH + c) * 9 + k] : (_Float16)0.f;
    }
  }
}

// ---------------------------------------------------------------------------
// Kernel B: fully fused. Block = 16-px strip (b, i, j0), 128 thr, 8 blocks/CU
// (LDS 20160 B). R2 change: halved block size (was 32-px/256-thr/4 blk/CU).
// Same total work and identical per-wave phase shapes, but 8 independent
// 2-wave barrier domains per CU instead of 4x 4-wave domains -> each
// __syncthreads stalls half as many threads, and cross-block phase overlap
// (VMEM gather of one block under MFMA of another) doubles in granularity.
// Phases:
//  0. stage x1t patch (3 rows x 18 cols x 64ch) into btile-aliased LDS,
//     coalesced, padded stride 72 halfs.
//  1. offset GEMM: D[o][px], M=32 (18 used), N=16, K=576; B-frags via
//     ds_read_b128 from the staged patch -> offs (aliased into dead btile
//     space @9216 B; staged patch occupies bytes [0,7760)).
//  1.5 table build: 144 items (16 px x 9 k) compute bilinear weights
//     (f16 x4) + clamped corner coords (u8 x4, packed u32) once.
//  2. gather: tid = px*8+cg; 12 B broadcast read from tables; 4 coalesced
//     corner loads; packed-f16 interp -> half8 IS one B-frag slot ->
//     ds_write_b128 into frag-ordered btile (overwrites staged patch + offs).
//  3. main GEMM: D[oc][px], M=64, N=16, K=576, ds_read_b128 + MFMA.
// XCD band swizzle: each XCD owns 64 contiguous rows of one image.
// ---------------------------------------------------------------------------
__global__ __launch_bounds__(128, 4) void deform_all(
    const _Float16* __restrict__ x0t, const _Float16* __restrict__ x1t,
    const _Float16* __restrict__ pf, const float* __restrict__ pb,
    const _Float16* __restrict__ wf, float* __restrict__ out) {
  __shared__ __align__(16) _Float16 btile[18 * 64 * 8];       // 18432 B (aliased: phase0/1 x1 patch+offs, phase2/3 frag tile)
  __shared__ __align__(16) _Float16 wtab[144 * 4];            // 1152 B: bilinear weights per (px,k)
  __shared__ unsigned ctab[144];                              // 576 B: packed corner coords per (px,k)
  float* offs = (float*)&btile[4608];     // bytes [9216,10496): dead zone during phases 0/1

  int xcd = blockIdx.x & 7, local = blockIdx.x >> 3;
  int strip = xcd * 512 + local;            // 0..4095
  int jq = strip & 7, i = (strip >> 3) & 127, b = strip >> 10;
  int j0 = jq * 16;
  int tid = threadIdx.x;
  const _Float16* x0b = x0t + (size_t)b * HP * HP * CH;
  const _Float16* x1b = x1t + (size_t)b * HP * HP * CH;

  // ---- Phase 0: stage x1t patch rows i..i+2, cols j0..j0+17 (coalesced) ----
  {
#pragma unroll
    for (int it = 0; it < 4; it++) {
      int e = it * 128 + tid;               // 432 half8 chunks = 3*18*8
      if (e < 432) {
        int r = e / 144, rem = e - r * 144;
        int col = rem >> 3, cg8 = rem & 7;
        half8 v = *(const half8*)(x1b + ((size_t)(i + r) * HP + (j0 + col)) * CH + cg8 * 8);
        *(half8*)&btile[(r * 18 + col) * 72 + cg8 * 8] = v;
      }
    }
  }
  __syncthreads();

  // ---- Phase 1: offset GEMM (M=32 padded from 18, N=16, K=576) ----
  {
    int lane = tid & 63, mt = tid >> 6;
    int p = lane & 15, q = lane >> 4;
    const half8* pfv = (const half8*)pf;
    f32x4 acc = {0.f, 0.f, 0.f, 0.f};
#pragma unroll 3
    for (int s = 0; s < 18; s++) {
      int u = 4 * s + q, k = u >> 3, c0 = (u & 7) << 3;   // t = s*32+q*8 -> (k,c)
      int ki = (k * 86) >> 8, kj = k - ki * 3;            // k/3, k%3 for k<9
      half8 bfrag = *(const half8*)&btile[(ki * 18 + p + kj) * 72 + c0];
      acc = __builtin_amdgcn_mfma_f32_16x16x32_f16(pfv[(s * 2 + mt) * 64 + lane], bfrag, acc, 0, 0, 0);
    }
    int col = lane & 15, quad = lane >> 4;
#pragma unroll
    for (int r = 0; r < 4; r++) {
      int o = mt * 16 + quad * 4 + r;
      if (o < NOFF) offs[col * 20 + o] = acc[r] + pb[o];
    }
  }
  __syncthreads();

  // ---- Phase 1.5: build interp weight/coord tables, one item per (px,k) ----
  {
    auto build = [&](int px, int k) {
      float ox = offs[px * 20 + k];
      float oy = offs[px * 20 + k + 9];
      int ki = (k * 11) >> 5, kj = k - ki * 3;            // k/3, k%3 for k<9
      float pxr = (float)(i + ki) + ox;                   // padded coords
      float pyr = (float)(j0 + px + kj) + oy;
      float fx = floorf(pxr), fy = floorf(pyr);
      float qltx = fminf(fmaxf(fx, 0.f), 129.f);
      float qlty = fminf(fmaxf(fy, 0.f), 129.f);
      float qrbx = fminf(fmaxf(fx + 1.f, 0.f), 129.f);
      float qrby = fminf(fmaxf(fy + 1.f, 0.f), 129.f);
      float pxc = fminf(fmaxf(pxr, 0.f), 129.f);
      float pyc = fminf(fmaxf(pyr, 0.f), 129.f);
      half4 wv;
      wv[0] = (_Float16)((1.f + qltx - pxc) * (1.f + qlty - pyc));  // lt
      wv[1] = (_Float16)((1.f - qrbx + pxc) * (1.f - qrby + pyc));  // rb
      wv[2] = (_Float16)((1.f + qltx - pxc) * (1.f - qrby + pyc));  // lb
      wv[3] = (_Float16)((1.f - qrbx + pxc) * (1.f + qlty - pyc));  // rt
      *(half4*)&wtab[(px * 9 + k) * 4] = wv;
      ctab[px * 9 + k] = (unsigned)(int)qltx | ((unsigned)(int)qlty << 8) |
                         ((unsigned)(int)qrbx << 16) | ((unsigned)(int)qrby << 24);
    };
    build(tid >> 3, tid & 7);               // items k=0..7 for all 16 px
    if (tid < 16) build(tid, 8);            // items k=8
  }
  __syncthreads();

  // ---- Phase 2: coalesced gather + table-driven interp -> frag btile ----
  {
    int cg = tid & 7, px = tid >> 3;        // 16 px x 8 channel-chunks
    int c0 = cg * 8;
    int kgq = cg & 3, sh = cg >> 2;
    _Float16* wslot = &btile[(kgq * 16 + px) * 8];
    const _Float16* xb0 = x0b + c0;
#pragma unroll
    for (int k = 0; k < 9; k++) {
      half4 wv = *(const half4*)&wtab[(px * 9 + k) * 4];   // broadcast across cg
      unsigned cc = ctab[px * 9 + k];
      int ltx = cc & 255, lty = (cc >> 8) & 255;
      int rbx = (cc >> 16) & 255, rby = cc >> 24;
      const _Float16* rowl = xb0 + ltx * (HP * CH);
      const _Float16* rowr = xb0 + rbx * (HP * CH);
      half8 vlt = *(const half8*)(rowl + lty * CH);
      half8 vlb = *(const half8*)(rowl + rby * CH);
      half8 vrb = *(const half8*)(rowr + rby * CH);
      half8 vrt = *(const half8*)(rowr + lty * CH);
      half8 f = vlt * wv[0] + vrb * wv[1] + vlb * wv[2] + vrt * wv[3];
      int s = k * 2 + sh;                   // t = k*64 + c0 + jj -> frag (s,kgq,px)
      *(half8*)(wslot + s * 512) = f;       // 512 halfs per s-step
    }
  }
  __syncthreads();

  // ---- Phase 3: main GEMM, D[oc][px], M=64, N=16, K=576 ----
  {
    int lane = tid & 63, w = tid >> 6;
    int mt0 = w * 2;
    f32x4 acc0 = {0.f, 0.f, 0.f, 0.f}, acc1 = {0.f, 0.f, 0.f, 0.f};
    const half8* wfv = (const half8*)wf;
    const half8* bt = (const half8*)btile;
#pragma unroll 6
    for (int s = 0; s < 18; s++) {
      half8 bfrag = bt[s * 64 + lane];
      acc0 = __builtin_amdgcn_mfma_f32_16x16x32_f16(wfv[(s * 4 + mt0) * 64 + lane], bfrag, acc0, 0, 0, 0);
      acc1 = __builtin_amdgcn_mfma_f32_16x16x32_f16(wfv[(s * 4 + mt0 + 1) * 64 + lane], bfrag, acc1, 0, 0, 0);
    }
    int col = lane & 15, quad = lane >> 4;
    int jo = j0 + col;
#pragma unroll
    for (int r = 0; r < 4; r++) {
      int oc0 = mt0 * 16 + quad * 4 + r;
      int oc1 = (mt0 + 1) * 16 + quad * 4 + r;
      out[((b * OC + oc0) * HH + i) * WW + jo] = acc0[r];
      out[((b * OC + oc1) * HH + i) * WW + jo] = acc1[r];
    }
  }
}

// ---------------------------------------------------------------------------
extern "C" void kernel_launch(void* const* d_in, const int* in_sizes, int n_in,
                              void* d_out, int out_size, void* d_ws, size_t ws_size,
                              hipStream_t stream) {
  const float* x0 = (const float*)d_in[0];
  const float* x1 = (const float*)d_in[1];
  const float* pw = (const float*)d_in[2];
  const float* pb = (const float*)d_in[3];
  const float* cw = (const float*)d_in[4];
  float* out = (float*)d_out;

  _Float16* wfrag  = (_Float16*)((char*)d_ws + WF_OFF);
  _Float16* pwfrag = (_Float16*)((char*)d_ws + PF_OFF);
  _Float16* x0t    = (_Float16*)((char*)d_ws + X0T_OFF);
  _Float16* x1t    = (_Float16*)((char*)d_ws + X1T_OFF);

  prep_all<<<dim3(2280), dim3(256), 0, stream>>>(x0, x1, cw, pw, x0t, x1t, wfrag, pwfrag);
  deform_all<<<dim3(4096), dim3(128), 0, stream>>>(x0t, x1t, pwfrag, pb, wfrag, out);
}

// Round 3
// 113.538 us; speedup vs baseline: 1.0398x; 1.0398x over previous
//
#include <hip/hip_runtime.h>

// Problem: b=4, c=64, h=w=128, ks=3, N=9, offset ch=18, oc=64. Padded HP=130.
#define BATCH 4
#define CH    64
#define HH    128
#define WW    128
#define HW    (HH*WW)
#define HP    130
#define NOFF  18
#define OC    64

typedef _Float16 half8 __attribute__((ext_vector_type(8)));
typedef _Float16 half4 __attribute__((ext_vector_type(4)));
typedef float f32x4 __attribute__((ext_vector_type(4)));

// ws layout (bytes):
//   wf  @ 0      : 36864 f16 (main A-frags)    pf @ 73728: 18432 f16
//   x0t @ 110592 : 4*130*130*64 f16 (padded NHWC, zero ring)
//   x1t @ 8763392: same                        total 17416192 B
#define WF_OFF  0
#define PF_OFF  73728
#define X0T_OFF 110592
#define X1T_OFF 8763392

// ---------------------------------------------------------------------------
// Kernel A: blocks 0..2047 transpose half-rows NCHW f32 -> padded NHWC f16;
// 2048..2063 zero ring rows; 2064..2279 A-fragments (k-major t = k*64+c).
// ---------------------------------------------------------------------------
__global__ __launch_bounds__(256) void prep_all(
    const float* __restrict__ x0, const float* __restrict__ x1,
    const float* __restrict__ cw, const float* __restrict__ pw,
    _Float16* __restrict__ x0t, _Float16* __restrict__ x1t,
    _Float16* __restrict__ wf, _Float16* __restrict__ pf) {
  int blk = blockIdx.x, tid = threadIdx.x;
  if (blk < 2048) {
    __shared__ float tile[64 * 66];
    int jh = blk & 1, i = (blk >> 1) & 127, b = (blk >> 8) & 3, which = blk >> 10;
    const float* src = which ? x1 : x0;
    _Float16* dst = which ? x1t : x0t;
#pragma unroll
    for (int it = 0; it < 4; it++) {
      int idx = it * 256 + tid;            // 1024 float4 = 64c x 64j
      int c = idx >> 4, j4 = (idx & 15) << 2;
      float4 v = *(const float4*)(src + (size_t)(b * CH + c) * HW + i * WW + jh * 64 + j4);
      *(float4*)&tile[c * 66 + j4] = v;
    }
    __syncthreads();
    int jl = tid >> 2, cq = (tid & 3) << 4;
    _Float16* dp = dst + ((size_t)(b * HP + i + 1) * HP + (jh * 64 + jl + 1)) * CH + cq;
#pragma unroll
    for (int h = 0; h < 2; h++) {
      half8 v;
#pragma unroll
      for (int cc = 0; cc < 8; cc++) v[cc] = (_Float16)tile[(cq + h * 8 + cc) * 66 + jl];
      *(half8*)(dp + h * 8) = v;
    }
    if (tid < 8) {                          // ring column jo=0 (jh0) / jo=129 (jh1)
      int jo = jh ? (HP - 1) : 0;
      _Float16* zp = dst + ((size_t)(b * HP + i + 1) * HP + jo) * CH + tid * 8;
      int4 z = {0, 0, 0, 0};
      *(int4*)zp = z;
    }
  } else if (blk < 2064) {
    int z = blk - 2048;
    int which = z >> 3, b = (z >> 1) & 3, top = z & 1;
    _Float16* dst = (which ? x1t : x0t) + ((size_t)(b * HP + top * (HP - 1)) * HP) * CH;
    int4 zz = {0, 0, 0, 0};
    for (int e = tid; e < 1040; e += 256) *(int4*)((char*)dst + e * 16) = zz;
  } else {
    int gid = (blk - 2064) * 256 + tid;     // 216*256 = 36864 + 18432
    if (gid < 36864) {
      int j = gid & 7, lane = (gid >> 3) & 63, mt = (gid >> 9) & 3, s = gid >> 11;
      int oc = mt * 16 + (lane & 15);
      int t = s * 32 + (lane >> 4) * 8 + j;
      int k = t >> 6, c = t & 63;
      wf[gid] = (_Float16)cw[(oc * CH + c) * 9 + k];
    } else {
      int g = gid - 36864;
      int j = g & 7, lane = (g >> 3) & 63, mt = (g >> 9) & 1, s = g >> 10;
      int o = mt * 16 + (lane & 15);
      int t = s * 32 + (lane >> 4) * 8 + j;
      int k = t >> 6, c = t & 63;
      pf[g] = (o < NOFF) ? (_Float16)pw[(o * CH + c) * 9 + k] : (_Float16)0.f;
    }
  }
}

// ---------------------------------------------------------------------------
// Kernel B: fully fused. Block = 32-px strip (b, i, j0), 256 thr, 4 blocks/CU
// (LDS 40320 B). R3 change: A-frag reuse across n-tiles. Each wave now owns
// ONE m-tile and computes BOTH 16-px n-tiles, loading each A-frag once and
// feeding two MFMAs. Cuts wf L2 traffic per block 147->73.7 KB and pf
// 73.7->36.9 KB (-226 MB = -28% of kernel L2 traffic; A-frags were 453 MB,
// larger than the gather's 302 MB). Phases 0/1.5/2 identical to the
// best-measured R0 variant.
//  0. stage x1t patch (3 rows x 34 cols x 64ch) into btile-aliased LDS,
//     coalesced, padded stride 72 halfs.
//  1. offset GEMM: D[o][px], M=32 (18 used), K=576; waves 0-1 own m-tile w,
//     iterate nt=0,1; B-frags via ds_read_b128 from staged patch -> offs.
//  1.5 table build: 288 items (32 px x 9 k) compute bilinear weights
//     (f16 x4) + clamped corner coords (u8 x4, packed u32) once.
//  2. gather: tid = px*8+cg; 12 B broadcast read from tables; 4 coalesced
//     corner loads; packed-f16 interp -> half8 IS one B-frag slot ->
//     ds_write_b128 into frag-ordered btile (overwrites staged patch + offs).
//  3. main GEMM: D[oc][px], M=64, K=576; wave w owns m-tile w, iterates
//     nt=0,1 sharing each A-frag.
// XCD band swizzle: each XCD owns 64 contiguous rows of one image.
// ---------------------------------------------------------------------------
__global__ __launch_bounds__(256, 4) void deform_all(
    const _Float16* __restrict__ x0t, const _Float16* __restrict__ x1t,
    const _Float16* __restrict__ pf, const float* __restrict__ pb,
    const _Float16* __restrict__ wf, float* __restrict__ out) {
  __shared__ __align__(16) _Float16 btile[2 * 18 * 64 * 8];   // 36864 B (aliased: phase0/1 x1 patch+offs, phase2/3 frag tile)
  __shared__ __align__(16) _Float16 wtab[288 * 4];            // 2304 B: bilinear weights per (px,k)
  __shared__ unsigned ctab[288];                              // 1152 B: packed corner coords per (px,k)
  float* offs = (float*)&btile[12288];    // bytes [24576,27136): dead zone during phases 0/1

  int xcd = blockIdx.x & 7, local = blockIdx.x >> 3;
  int strip = xcd * 256 + local;            // 0..2047
  int jq2 = strip & 3, i = (strip >> 2) & 127, b = strip >> 9;
  int j0 = jq2 * 32;
  int tid = threadIdx.x;
  const _Float16* x0b = x0t + (size_t)b * HP * HP * CH;
  const _Float16* x1b = x1t + (size_t)b * HP * HP * CH;

  // ---- Phase 0: stage x1t patch rows i..i+2, cols j0..j0+33 (coalesced) ----
  {
#pragma unroll
    for (int it = 0; it < 4; it++) {
      int e = it * 256 + tid;               // 816 half8 chunks = 3*34*8
      if (e < 816) {
        int r = e / 272, rem = e - r * 272;
        int col = rem >> 3, cg8 = rem & 7;
        half8 v = *(const half8*)(x1b + ((size_t)(i + r) * HP + (j0 + col)) * CH + cg8 * 8);
        *(half8*)&btile[(r * 34 + col) * 72 + cg8 * 8] = v;
      }
    }
  }
  __syncthreads();

  // ---- Phase 1: offset GEMM (M=32 padded from 18, K=576), A-reuse over nt ----
  {
    int lane = tid & 63, w = tid >> 6;
    if (w < 2) {                            // wave w owns m-tile w; waves 2-3 idle
      int p = lane & 15, q = lane >> 4;
      const half8* pfv = (const half8*)pf;
      f32x4 acc0 = {0.f, 0.f, 0.f, 0.f}, acc1 = {0.f, 0.f, 0.f, 0.f};
#pragma unroll 3
      for (int s = 0; s < 18; s++) {
        int u = 4 * s + q, k = u >> 3, c0 = (u & 7) << 3;   // t = s*32+q*8 -> (k,c)
        int ki = (k * 86) >> 8, kj = k - ki * 3;            // k/3, k%3 for k<9
        half8 a = pfv[(s * 2 + w) * 64 + lane];
        half8 b0 = *(const half8*)&btile[(ki * 34 + p + kj) * 72 + c0];
        half8 b1 = *(const half8*)&btile[(ki * 34 + 16 + p + kj) * 72 + c0];
        acc0 = __builtin_amdgcn_mfma_f32_16x16x32_f16(a, b0, acc0, 0, 0, 0);
        acc1 = __builtin_amdgcn_mfma_f32_16x16x32_f16(a, b1, acc1, 0, 0, 0);
      }
      int col = lane & 15, quad = lane >> 4;
#pragma unroll
      for (int r = 0; r < 4; r++) {
        int o = w * 16 + quad * 4 + r;
        if (o < NOFF) {
          float bias = pb[o];
          offs[col * 20 + o] = acc0[r] + bias;
          offs[(16 + col) * 20 + o] = acc1[r] + bias;
        }
      }
    }
  }
  __syncthreads();

  // ---- Phase 1.5: build interp weight/coord tables, one item per (px,k) ----
  {
    auto build = [&](int px, int k) {
      float ox = offs[px * 20 + k];
      float oy = offs[px * 20 + k + 9];
      int ki = (k * 11) >> 5, kj = k - ki * 3;            // k/3, k%3 for k<9
      float pxr = (float)(i + ki) + ox;                   // padded coords
      float pyr = (float)(j0 + px + kj) + oy;
      float fx = floorf(pxr), fy = floorf(pyr);
      float qltx = fminf(fmaxf(fx, 0.f), 129.f);
      float qlty = fminf(fmaxf(fy, 0.f), 129.f);
      float qrbx = fminf(fmaxf(fx + 1.f, 0.f), 129.f);
      float qrby = fminf(fmaxf(fy + 1.f, 0.f), 129.f);
      float pxc = fminf(fmaxf(pxr, 0.f), 129.f);
      float pyc = fminf(fmaxf(pyr, 0.f), 129.f);
      half4 wv;
      wv[0] = (_Float16)((1.f + qltx - pxc) * (1.f + qlty - pyc));  // lt
      wv[1] = (_Float16)((1.f - qrbx + pxc) * (1.f - qrby + pyc));  // rb
      wv[2] = (_Float16)((1.f + qltx - pxc) * (1.f - qrby + pyc));  // lb
      wv[3] = (_Float16)((1.f - qrbx + pxc) * (1.f + qlty - pyc));  // rt
      *(half4*)&wtab[(px * 9 + k) * 4] = wv;
      ctab[px * 9 + k] = (unsigned)(int)qltx | ((unsigned)(int)qlty << 8) |
                         ((unsigned)(int)qrbx << 16) | ((unsigned)(int)qrby << 24);
    };
    build(tid >> 3, tid & 7);               // items k=0..7 for all 32 px
    if (tid < 32) build(tid, 8);            // items k=8
  }
  __syncthreads();

  // ---- Phase 2: coalesced gather + table-driven interp -> frag btile ----
  {
    int cg = tid & 7, px = tid >> 3;        // 32 px x 8 channel-chunks
    int c0 = cg * 8;
    int nt = px >> 4, pxl = px & 15, kgq = cg & 3, sh = cg >> 2;
    _Float16* wslot = &btile[(((nt * 18) * 4 + kgq) * 16 + pxl) * 8];
    const _Float16* xb0 = x0b + c0;
#pragma unroll
    for (int k = 0; k < 9; k++) {
      half4 wv = *(const half4*)&wtab[(px * 9 + k) * 4];   // broadcast across cg
      unsigned cc = ctab[px * 9 + k];
      int ltx = cc & 255, lty = (cc >> 8) & 255;
      int rbx = (cc >> 16) & 255, rby = cc >> 24;
      const _Float16* rowl = xb0 + ltx * (HP * CH);
      const _Float16* rowr = xb0 + rbx * (HP * CH);
      half8 vlt = *(const half8*)(rowl + lty * CH);
      half8 vlb = *(const half8*)(rowl + rby * CH);
      half8 vrb = *(const half8*)(rowr + rby * CH);
      half8 vrt = *(const half8*)(rowr + lty * CH);
      half8 f = vlt * wv[0] + vrb * wv[1] + vlb * wv[2] + vrt * wv[3];
      int s = k * 2 + sh;                   // t = k*64 + c0 + jj -> frag (s,kgq,pxl)
      *(half8*)(wslot + s * 512) = f;       // 512 halfs per s-step
    }
  }
  __syncthreads();

  // ---- Phase 3: main GEMM, D[oc][px], M=64, K=576, A-reuse over nt ----
  {
    int lane = tid & 63, w = tid >> 6;      // wave w = m-tile 0..3
    f32x4 acc0 = {0.f, 0.f, 0.f, 0.f}, acc1 = {0.f, 0.f, 0.f, 0.f};
    const half8* wfv = (const half8*)wf;
    const half8* bt0 = (const half8*)&btile[0];
    const half8* bt1 = (const half8*)&btile[18 * 512];
#pragma unroll 6
    for (int s = 0; s < 18; s++) {
      half8 a = wfv[(s * 4 + w) * 64 + lane];
      acc0 = __builtin_amdgcn_mfma_f32_16x16x32_f16(a, bt0[s * 64 + lane], acc0, 0, 0, 0);
      acc1 = __builtin_amdgcn_mfma_f32_16x16x32_f16(a, bt1[s * 64 + lane], acc1, 0, 0, 0);
    }
    int col = lane & 15, quad = lane >> 4;
#pragma unroll
    for (int r = 0; r < 4; r++) {
      int oc = w * 16 + quad * 4 + r;
      float* orow = out + ((size_t)(b * OC + oc) * HH + i) * WW;
      orow[j0 + col] = acc0[r];
      orow[j0 + 16 + col] = acc1[r];
    }
  }
}

// ---------------------------------------------------------------------------
extern "C" void kernel_launch(void* const* d_in, const int* in_sizes, int n_in,
                              void* d_out, int out_size, void* d_ws, size_t ws_size,
                              hipStream_t stream) {
  const float* x0 = (const float*)d_in[0];
  const float* x1 = (const float*)d_in[1];
  const float* pw = (const float*)d_in[2];
  const float* pb = (const float*)d_in[3];
  const float* cw = (const float*)d_in[4];
  float* out = (float*)d_out;

  _Float16* wfrag  = (_Float16*)((char*)d_ws + WF_OFF);
  _Float16* pwfrag = (_Float16*)((char*)d_ws + PF_OFF);
  _Float16* x0t    = (_Float16*)((char*)d_ws + X0T_OFF);
  _Float16* x1t    = (_Float16*)((char*)d_ws + X1T_OFF);

  prep_all<<<dim3(2280), dim3(256), 0, stream>>>(x0, x1, cw, pw, x0t, x1t, wfrag, pwfrag);
  deform_all<<<dim3(2048), dim3(256), 0, stream>>>(x0t, x1t, pwfrag, pb, wfrag, out);
}